// Round 12
// baseline (1099.544 us; speedup 1.0000x reference)
//
#include <hip/hip_runtime.h>

// FirstOrderCondRNN: B=256 batches, T=61 (60 scan steps).
// One block per batch; all recurrent state on-chip.
// R12 = R10's SINGLE-BARRIER structure with the spill source removed.
// R10 proved the redundant-DAN + __shfl scheme bit-exact but died of
// register spills (VGPR_Count=128, wrreg demand ~150+, FETCH 585MB /
// WRITE 1.4GB of scratch). R11 proved R9 wasn't spilling => wrreg was
// the sole culprit. Here: A-lanes read Wr from LDS (s_Wr, WRSTR=108,
// costs ~4us vs regs per R7), register demand ~80 -> no spills.
// Structure win: waves 2-7 skip Phase A and start chunk/store E-work
// right after their own 20-row DAN dot -> 6/8 waves overlap E with A;
// ONE barrier per step. Keeps R9 4-chain/tree, nt stores, XCD swizzle.

#define NKC   200
#define NREC  100
#define TSTEP 61
#define NSTEP 60
#define WRSTR 108   // padded Wr row stride (16B-aligned rows, full bank coverage)
#define PSTR  52    // padded partial row stride
#define NTHR  512

typedef float vfloat4 __attribute__((ext_vector_type(4)));

__device__ __forceinline__ void bar_lds() {
    __builtin_amdgcn_sched_barrier(0);
    asm volatile("s_waitcnt lgkmcnt(0)");
    __builtin_amdgcn_s_barrier();
    __builtin_amdgcn_sched_barrier(0);
}

__device__ __forceinline__ void nt_store4(float* p, float4 v) {
    vfloat4 t;
    t.x = v.x; t.y = v.y; t.z = v.z; t.w = v.w;
    __builtin_nontemporal_store(t, (vfloat4*)p);
}
__device__ __forceinline__ void nt_store1(float* p, float v) {
    __builtin_nontemporal_store(v, p);
}

__global__ __launch_bounds__(NTHR, 1) void cond_rnn_kernel(
    const float* __restrict__ r_kc, const float* __restrict__ r_ext,
    const float* __restrict__ timev, const float* __restrict__ W0_W,
    const float* __restrict__ W0_w, const float* __restrict__ W_recur,
    const float* __restrict__ W_ext, const float* __restrict__ bias,
    const float* __restrict__ W_readout, float* __restrict__ out, int B)
{
    int b = blockIdx.x;
    if ((B & 7) == 0) {
        const int cpx = B >> 3;
        b = (blockIdx.x & 7) * cpx + (blockIdx.x >> 3);
    }
    const int tid  = threadIdx.x;
    const int lane = tid & 63;
    const float dt  = timev[1] - timev[0];   // 0.5
    const float dtw = dt / 5.0f;             // dt / TAU_W

    __shared__ __align__(16) float s_rk[TSTEP * NKC];     // [t][k], 48.8 KB
    __shared__ __align__(16) float s_re[128];             // [e][t]
    __shared__ __align__(16) float s_Wr[NREC * WRSTR];    // 43.2 KB (A-lanes)
    __shared__ __align__(16) float s_Wro[32];
    __shared__ __align__(16) float s_r[2][112];           // double-buffered rates
    __shared__ __align__(16) float s_Wrd[20 * 100];       // Wr DAN rows 80..99, 8 KB
    __shared__ __align__(16) float s_part2[2][20 * PSTR]; // double-buffered I_kc partials

    // ---------------- init ----------------
    const float* rk_b = r_kc + (size_t)b * (NKC * TSTEP);
    for (int f = tid; f < NKC * TSTEP; f += NTHR) {
        int k = f / TSTEP, t = f - k * TSTEP;
        s_rk[t * NKC + k] = rk_b[f];               // transpose to [t][k]
    }
    const float* re_b = r_ext + (size_t)b * (2 * TSTEP);
    if (tid < 2 * TSTEP) s_re[tid] = re_b[tid];
    for (int f = tid; f < NREC * NREC; f += NTHR) {
        int s = f / NREC, j = f - s * NREC;
        float v = W_recur[f];
        if (s < 20 && j >= 80) v = 0.f;            // Wr[:n_mbon, -n_dan:] = 0
        s_Wr[s * WRSTR + j] = v;
    }
    for (int f = tid; f < 20 * 100; f += NTHR)     // DAN rows of Wr (unzeroed rows 80-99)
        s_Wrd[f] = W_recur[80 * NREC + f];

    if (tid < 20)  s_Wro[tid] = W_readout[tid];
    if (tid < 100) s_r[0][tid] = (tid < 20) ? 0.f : 0.1f;

    float my_bias = 0.f, we0 = 0.f, we1 = 0.f;
    if (tid < 100) my_bias = bias[tid];
    if (tid >= 20 && tid < 80) { we0 = W_ext[(tid - 20) * 2]; we1 = W_ext[(tid - 20) * 2 + 1]; }
    float r_mine = (tid < 20) ? 0.f : 0.1f;

    // redundant DAN state (per wave, lanes 0-19 meaningful)
    const int   drow     = (lane < 20) ? lane : 0;
    const float dan_bias = bias[80 + drow];
    float dan_rbd = 0.1f;

    // output sections
    float* out_r  = out;                              // [61][B][100]
    float* out_W  = out + (size_t)TSTEP * B * 100;    // [61][B][4000]
    float* out_wt = out_W + (size_t)TSTEP * B * 4000; // [61][B][4000]
    float* out_ro = out_wt + (size_t)TSTEP * B * 4000;// [61][B]

    float4 Wreg[2], wtreg[2], rbkreg[2], rkc[2];
    const float* W0Wb = W0_W + (size_t)b * 4000;
    const float* W0wb = W0_w + (size_t)b * 4000;
    #pragma unroll
    for (int i = 0; i < 2; ++i) {
        int c = tid + NTHR * i;
        if (c < 1000) {
            Wreg[i]  = *(const float4*)(W0Wb + 4 * c);
            wtreg[i] = *(const float4*)(W0wb + 4 * c);
            nt_store4(out_W  + (size_t)b * 4000 + 4 * c, Wreg[i]);   // t=0 dumps
            nt_store4(out_wt + (size_t)b * 4000 + 4 * c, wtreg[i]);
        }
    }
    if (tid < 100) nt_store1(out_r + (size_t)b * 100 + tid, r_mine);

    __syncthreads();

    // initial rbk = rk[:,0]; initial I_kc partials into s_part2[0]
    #pragma unroll
    for (int i = 0; i < 2; ++i) {
        int c = tid + NTHR * i;
        if (c < 1000) {
            int k0 = (4 * c) % NKC;
            int m  = c / 50;
            float4 rk0 = *(const float4*)(s_rk + k0);
            rbkreg[i] = rk0;
            rkc[i]    = rk0;
            float4 w = Wreg[i];
            s_part2[0][m * PSTR + (c % 50)] =
                w.x * rk0.x + w.y * rk0.y + w.z * rk0.z + w.w * rk0.w;
        }
    }
    if (tid == 255) {
        float ro = 0.f;
        #pragma unroll
        for (int mm = 0; mm < 20; ++mm) ro += s_Wro[mm] * s_r[0][mm];
        nt_store1(out_ro + b, ro);   // t=0 readout
    }
    __syncthreads();

    // ---------------- time loop: ONE phase, ONE barrier per step ----------------
    for (int it = 0; it < NSTEP; ++it) {
        const int cur = it & 1, nxt = cur ^ 1;

        // (1) redundant DAN rates: every wave, lanes 0-19 (bit-equal to A-lanes)
        float dan_rn;
        {
            float a0 = 0.f, a1 = 0.f, a2 = 0.f, a3 = 0.f;
            const float* wd = s_Wrd + drow * 100;
            #pragma unroll
            for (int j4 = 0; j4 < 24; j4 += 4) {
                {
                    float4 w4 = *(const float4*)(wd + 4 * j4);
                    float4 r4 = *(const float4*)(&s_r[cur][4 * j4]);
                    a0 = fmaf(w4.x, r4.x, a0); a0 = fmaf(w4.y, r4.y, a0);
                    a0 = fmaf(w4.z, r4.z, a0); a0 = fmaf(w4.w, r4.w, a0);
                }
                {
                    float4 w4 = *(const float4*)(wd + 4 * (j4 + 1));
                    float4 r4 = *(const float4*)(&s_r[cur][4 * (j4 + 1)]);
                    a1 = fmaf(w4.x, r4.x, a1); a1 = fmaf(w4.y, r4.y, a1);
                    a1 = fmaf(w4.z, r4.z, a1); a1 = fmaf(w4.w, r4.w, a1);
                }
                {
                    float4 w4 = *(const float4*)(wd + 4 * (j4 + 2));
                    float4 r4 = *(const float4*)(&s_r[cur][4 * (j4 + 2)]);
                    a2 = fmaf(w4.x, r4.x, a2); a2 = fmaf(w4.y, r4.y, a2);
                    a2 = fmaf(w4.z, r4.z, a2); a2 = fmaf(w4.w, r4.w, a2);
                }
                {
                    float4 w4 = *(const float4*)(wd + 4 * (j4 + 3));
                    float4 r4 = *(const float4*)(&s_r[cur][4 * (j4 + 3)]);
                    a3 = fmaf(w4.x, r4.x, a3); a3 = fmaf(w4.y, r4.y, a3);
                    a3 = fmaf(w4.z, r4.z, a3); a3 = fmaf(w4.w, r4.w, a3);
                }
            }
            {   // j4 = 24 tail
                float4 w4 = *(const float4*)(wd + 96);
                float4 r4 = *(const float4*)(&s_r[cur][96]);
                a0 = fmaf(w4.x, r4.x, a0); a0 = fmaf(w4.y, r4.y, a0);
                a0 = fmaf(w4.z, r4.z, a0); a0 = fmaf(w4.w, r4.w, a0);
            }
            float acc = dan_bias;
            acc += (a0 + a1) + (a2 + a3);
            float drive = acc > 0.f ? acc : 0.f;
            float rdp = s_r[cur][80 + drow];
            dan_rn = rdp + dt * (drive - rdp);
            dan_rbd += (dan_rn - dan_rbd) * dtw;
        }

        // (2) A-lanes: full r update (Wr from LDS; 4-chain + tree, R9 order)
        float rnA = 0.f;
        if (tid < 100) {
            float acc = my_bias;
            if (tid < 20) {                       // MBON: + I_kc, tree-summed
                const float* pp = s_part2[cur] + tid * PSTR;
                float4 s01 = *(const float4*)(pp + 0)  + *(const float4*)(pp + 4);
                float4 s23 = *(const float4*)(pp + 8)  + *(const float4*)(pp + 12);
                float4 s45 = *(const float4*)(pp + 16) + *(const float4*)(pp + 20);
                float4 s67 = *(const float4*)(pp + 24) + *(const float4*)(pp + 28);
                float4 s89 = *(const float4*)(pp + 32) + *(const float4*)(pp + 36);
                float4 sab = *(const float4*)(pp + 40) + *(const float4*)(pp + 44);
                float4 t0 = s01 + s23;
                float4 t1 = s45 + s67;
                float4 t2 = s89 + sab;
                float4 u  = t0 + t1;
                u = u + t2;
                float tail = (pp[48] + pp[49]);
                acc += ((u.x + u.y) + (u.z + u.w)) + tail;
            } else if (tid < 80) {                // FBN
                acc = fmaf(we0, s_re[it], acc);
                acc = fmaf(we1, s_re[TSTEP + it], acc);
            }
            const float* wr = s_Wr + tid * WRSTR;
            float a0 = 0.f, a1 = 0.f, a2 = 0.f, a3 = 0.f;
            #pragma unroll
            for (int j4 = 0; j4 < 24; j4 += 4) {
                {
                    float4 w4 = *(const float4*)(wr + 4 * j4);
                    float4 r4 = *(const float4*)(&s_r[cur][4 * j4]);
                    a0 = fmaf(w4.x, r4.x, a0); a0 = fmaf(w4.y, r4.y, a0);
                    a0 = fmaf(w4.z, r4.z, a0); a0 = fmaf(w4.w, r4.w, a0);
                }
                {
                    float4 w4 = *(const float4*)(wr + 4 * (j4 + 1));
                    float4 r4 = *(const float4*)(&s_r[cur][4 * (j4 + 1)]);
                    a1 = fmaf(w4.x, r4.x, a1); a1 = fmaf(w4.y, r4.y, a1);
                    a1 = fmaf(w4.z, r4.z, a1); a1 = fmaf(w4.w, r4.w, a1);
                }
                {
                    float4 w4 = *(const float4*)(wr + 4 * (j4 + 2));
                    float4 r4 = *(const float4*)(&s_r[cur][4 * (j4 + 2)]);
                    a2 = fmaf(w4.x, r4.x, a2); a2 = fmaf(w4.y, r4.y, a2);
                    a2 = fmaf(w4.z, r4.z, a2); a2 = fmaf(w4.w, r4.w, a2);
                }
                {
                    float4 w4 = *(const float4*)(wr + 4 * (j4 + 3));
                    float4 r4 = *(const float4*)(&s_r[cur][4 * (j4 + 3)]);
                    a3 = fmaf(w4.x, r4.x, a3); a3 = fmaf(w4.y, r4.y, a3);
                    a3 = fmaf(w4.z, r4.z, a3); a3 = fmaf(w4.w, r4.w, a3);
                }
            }
            {   // j4 = 24 tail
                float4 w4 = *(const float4*)(wr + 96);
                float4 r4 = *(const float4*)(&s_r[cur][96]);
                a0 = fmaf(w4.x, r4.x, a0); a0 = fmaf(w4.y, r4.y, a0);
                a0 = fmaf(w4.z, r4.z, a0); a0 = fmaf(w4.w, r4.w, a0);
            }
            acc += (a0 + a1) + (a2 + a3);
            float drive = acc > 0.f ? acc : 0.f;
            float rn = r_mine + dt * (drive - r_mine);   // TAU_R = 1
            r_mine = rn;
            rnA = rn;
            s_r[nxt][tid] = rn;
            nt_store1(out_r + (size_t)(it + 1) * B * 100 + (size_t)b * 100 + tid, rn);
        }

        // (3) chunk updates: rdan/rbd via in-wave shuffle (no barrier needed;
        //     waves 2-7 reach here right after (1))
        float* oW  = out_W  + (size_t)(it + 1) * B * 4000 + (size_t)b * 4000;
        float* owt = out_wt + (size_t)(it + 1) * B * 4000 + (size_t)b * 4000;
        const float* rk_nx = s_rk + (it + 1) * NKC;
        #pragma unroll
        for (int i = 0; i < 2; ++i) {
            int c = tid + NTHR * i;
            if (c < 1000) {
                int k0 = (4 * c) % NKC;
                int m  = c / 50;
                float rdan = __shfl(dan_rn,  m);
                float rbdn = __shfl(dan_rbd, m);
                float4 rk4 = rkc[i];
                float4 rkn = *(const float4*)(rk_nx + k0);
                rkc[i] = rkn;
                float4 rb = rbkreg[i];
                rb.x += (rk4.x - rb.x) * dtw;  rb.y += (rk4.y - rb.y) * dtw;
                rb.z += (rk4.z - rb.z) * dtw;  rb.w += (rk4.w - rb.w) * dtw;
                rbkreg[i] = rb;
                float4 wt = wtreg[i];
                wt.x = fmaf(rbdn * rk4.x - rdan * rb.x, dt, wt.x);
                wt.y = fmaf(rbdn * rk4.y - rdan * rb.y, dt, wt.y);
                wt.z = fmaf(rbdn * rk4.z - rdan * rb.z, dt, wt.z);
                wt.w = fmaf(rbdn * rk4.w - rdan * rb.w, dt, wt.w);
                wtreg[i] = wt;
                float4 w = Wreg[i];
                w.x += (wt.x - w.x) * dtw;  w.y += (wt.y - w.y) * dtw;
                w.z += (wt.z - w.z) * dtw;  w.w += (wt.w - w.w) * dtw;
                w.x = fminf(fmaxf(w.x, 0.f), 0.05f);
                w.y = fminf(fmaxf(w.y, 0.f), 0.05f);
                w.z = fminf(fmaxf(w.z, 0.f), 0.05f);
                w.w = fminf(fmaxf(w.w, 0.f), 0.05f);
                Wreg[i] = w;
                s_part2[nxt][m * PSTR + (c % 50)] =
                    w.x * rkn.x + w.y * rkn.y + w.z * rkn.z + w.w * rkn.w;
                nt_store4(owt + 4 * c, wt);
                nt_store4(oW  + 4 * c, w);
            }
        }

        // (4) readout: wave-0 shuffle gather of in-register r_new MBONs
        if (tid < 64) {
            float q0 = 0.f, q1 = 0.f, q2 = 0.f, q3 = 0.f;
            #pragma unroll
            for (int mm = 0; mm < 20; mm += 4) {
                q0 = fmaf(s_Wro[mm],     __shfl(rnA, mm),     q0);
                q1 = fmaf(s_Wro[mm + 1], __shfl(rnA, mm + 1), q1);
                q2 = fmaf(s_Wro[mm + 2], __shfl(rnA, mm + 2), q2);
                q3 = fmaf(s_Wro[mm + 3], __shfl(rnA, mm + 3), q3);
            }
            if (tid == 0)
                nt_store1(out_ro + (size_t)(it + 1) * B + b, (q0 + q1) + (q2 + q3));
        }

        bar_lds();   // the ONLY barrier per step
    }
}

extern "C" void kernel_launch(void* const* d_in, const int* in_sizes, int n_in,
                              void* d_out, int out_size, void* d_ws, size_t ws_size,
                              hipStream_t stream) {
    const float* r_kc      = (const float*)d_in[0];
    const float* r_ext     = (const float*)d_in[1];
    const float* timev     = (const float*)d_in[2];
    // d_in[3] = n_batch (int scalar) — shape derived from in_sizes instead
    const float* W0_W      = (const float*)d_in[4];
    const float* W0_w      = (const float*)d_in[5];
    const float* W_recur   = (const float*)d_in[6];
    const float* W_ext     = (const float*)d_in[7];
    const float* bias      = (const float*)d_in[8];
    const float* W_readout = (const float*)d_in[9];

    const int B = in_sizes[0] / (NKC * TSTEP);   // 256
    cond_rnn_kernel<<<dim3(B), dim3(NTHR), 0, stream>>>(
        r_kc, r_ext, timev, W0_W, W0_w, W_recur, W_ext, bias, W_readout,
        (float*)d_out, B);
}

// Round 13
// 1099.010 us; speedup vs baseline: 1.0005x; 1.0005x over previous
//
#include <hip/hip_runtime.h>

// FirstOrderCondRNN: B=256 batches, T=61 (60 scan steps).
// One block per batch; all recurrent state on-chip.
// R13 = R12 (single-barrier structure) + amdgpu_waves_per_eu(2,2).
// R12's counters showed the SAME spill failure as R10 (VGPR_Count=128,
// FETCH 370MB, WRITE 2.17GB of scratch) -> the single-barrier structure
// has been built twice and measured zero times. R11 proved the attribute
// is harmless on non-spilling code and legalizes 256 VGPR/thread
// (8-wave block = exactly 2 waves/SIMD). Demand ~150 -> fits, no spill.
// Everything else identical to R12.

#define NKC   200
#define NREC  100
#define TSTEP 61
#define NSTEP 60
#define WRSTR 108   // padded Wr row stride (16B-aligned rows, full bank coverage)
#define PSTR  52    // padded partial row stride
#define NTHR  512

typedef float vfloat4 __attribute__((ext_vector_type(4)));

__device__ __forceinline__ void bar_lds() {
    __builtin_amdgcn_sched_barrier(0);
    asm volatile("s_waitcnt lgkmcnt(0)");
    __builtin_amdgcn_s_barrier();
    __builtin_amdgcn_sched_barrier(0);
}

__device__ __forceinline__ void nt_store4(float* p, float4 v) {
    vfloat4 t;
    t.x = v.x; t.y = v.y; t.z = v.z; t.w = v.w;
    __builtin_nontemporal_store(t, (vfloat4*)p);
}
__device__ __forceinline__ void nt_store1(float* p, float v) {
    __builtin_nontemporal_store(v, p);
}

__global__ __launch_bounds__(NTHR, 1)
__attribute__((amdgpu_waves_per_eu(2, 2)))
void cond_rnn_kernel(
    const float* __restrict__ r_kc, const float* __restrict__ r_ext,
    const float* __restrict__ timev, const float* __restrict__ W0_W,
    const float* __restrict__ W0_w, const float* __restrict__ W_recur,
    const float* __restrict__ W_ext, const float* __restrict__ bias,
    const float* __restrict__ W_readout, float* __restrict__ out, int B)
{
    int b = blockIdx.x;
    if ((B & 7) == 0) {
        const int cpx = B >> 3;
        b = (blockIdx.x & 7) * cpx + (blockIdx.x >> 3);
    }
    const int tid  = threadIdx.x;
    const int lane = tid & 63;
    const float dt  = timev[1] - timev[0];   // 0.5
    const float dtw = dt / 5.0f;             // dt / TAU_W

    __shared__ __align__(16) float s_rk[TSTEP * NKC];     // [t][k], 48.8 KB
    __shared__ __align__(16) float s_re[128];             // [e][t]
    __shared__ __align__(16) float s_Wr[NREC * WRSTR];    // 43.2 KB (A-lanes)
    __shared__ __align__(16) float s_Wro[32];
    __shared__ __align__(16) float s_r[2][112];           // double-buffered rates
    __shared__ __align__(16) float s_Wrd[20 * 100];       // Wr DAN rows 80..99, 8 KB
    __shared__ __align__(16) float s_part2[2][20 * PSTR]; // double-buffered I_kc partials

    // ---------------- init ----------------
    const float* rk_b = r_kc + (size_t)b * (NKC * TSTEP);
    for (int f = tid; f < NKC * TSTEP; f += NTHR) {
        int k = f / TSTEP, t = f - k * TSTEP;
        s_rk[t * NKC + k] = rk_b[f];               // transpose to [t][k]
    }
    const float* re_b = r_ext + (size_t)b * (2 * TSTEP);
    if (tid < 2 * TSTEP) s_re[tid] = re_b[tid];
    for (int f = tid; f < NREC * NREC; f += NTHR) {
        int s = f / NREC, j = f - s * NREC;
        float v = W_recur[f];
        if (s < 20 && j >= 80) v = 0.f;            // Wr[:n_mbon, -n_dan:] = 0
        s_Wr[s * WRSTR + j] = v;
    }
    for (int f = tid; f < 20 * 100; f += NTHR)     // DAN rows of Wr (rows 80-99)
        s_Wrd[f] = W_recur[80 * NREC + f];

    if (tid < 20)  s_Wro[tid] = W_readout[tid];
    if (tid < 100) s_r[0][tid] = (tid < 20) ? 0.f : 0.1f;

    float my_bias = 0.f, we0 = 0.f, we1 = 0.f;
    if (tid < 100) my_bias = bias[tid];
    if (tid >= 20 && tid < 80) { we0 = W_ext[(tid - 20) * 2]; we1 = W_ext[(tid - 20) * 2 + 1]; }
    float r_mine = (tid < 20) ? 0.f : 0.1f;

    // redundant DAN state (per wave, lanes 0-19 meaningful)
    const int   drow     = (lane < 20) ? lane : 0;
    const float dan_bias = bias[80 + drow];
    float dan_rbd = 0.1f;

    // output sections
    float* out_r  = out;                              // [61][B][100]
    float* out_W  = out + (size_t)TSTEP * B * 100;    // [61][B][4000]
    float* out_wt = out_W + (size_t)TSTEP * B * 4000; // [61][B][4000]
    float* out_ro = out_wt + (size_t)TSTEP * B * 4000;// [61][B]

    float4 Wreg[2], wtreg[2], rbkreg[2], rkc[2];
    const float* W0Wb = W0_W + (size_t)b * 4000;
    const float* W0wb = W0_w + (size_t)b * 4000;
    #pragma unroll
    for (int i = 0; i < 2; ++i) {
        int c = tid + NTHR * i;
        if (c < 1000) {
            Wreg[i]  = *(const float4*)(W0Wb + 4 * c);
            wtreg[i] = *(const float4*)(W0wb + 4 * c);
            nt_store4(out_W  + (size_t)b * 4000 + 4 * c, Wreg[i]);   // t=0 dumps
            nt_store4(out_wt + (size_t)b * 4000 + 4 * c, wtreg[i]);
        }
    }
    if (tid < 100) nt_store1(out_r + (size_t)b * 100 + tid, r_mine);

    __syncthreads();

    // initial rbk = rk[:,0]; initial I_kc partials into s_part2[0]
    #pragma unroll
    for (int i = 0; i < 2; ++i) {
        int c = tid + NTHR * i;
        if (c < 1000) {
            int k0 = (4 * c) % NKC;
            int m  = c / 50;
            float4 rk0 = *(const float4*)(s_rk + k0);
            rbkreg[i] = rk0;
            rkc[i]    = rk0;
            float4 w = Wreg[i];
            s_part2[0][m * PSTR + (c % 50)] =
                w.x * rk0.x + w.y * rk0.y + w.z * rk0.z + w.w * rk0.w;
        }
    }
    if (tid == 255) {
        float ro = 0.f;
        #pragma unroll
        for (int mm = 0; mm < 20; ++mm) ro += s_Wro[mm] * s_r[0][mm];
        nt_store1(out_ro + b, ro);   // t=0 readout
    }
    __syncthreads();

    // ---------------- time loop: ONE phase, ONE barrier per step ----------------
    for (int it = 0; it < NSTEP; ++it) {
        const int cur = it & 1, nxt = cur ^ 1;

        // (1) redundant DAN rates: every wave, lanes 0-19 (bit-equal to A-lanes)
        float dan_rn;
        {
            float a0 = 0.f, a1 = 0.f, a2 = 0.f, a3 = 0.f;
            const float* wd = s_Wrd + drow * 100;
            #pragma unroll
            for (int j4 = 0; j4 < 24; j4 += 4) {
                {
                    float4 w4 = *(const float4*)(wd + 4 * j4);
                    float4 r4 = *(const float4*)(&s_r[cur][4 * j4]);
                    a0 = fmaf(w4.x, r4.x, a0); a0 = fmaf(w4.y, r4.y, a0);
                    a0 = fmaf(w4.z, r4.z, a0); a0 = fmaf(w4.w, r4.w, a0);
                }
                {
                    float4 w4 = *(const float4*)(wd + 4 * (j4 + 1));
                    float4 r4 = *(const float4*)(&s_r[cur][4 * (j4 + 1)]);
                    a1 = fmaf(w4.x, r4.x, a1); a1 = fmaf(w4.y, r4.y, a1);
                    a1 = fmaf(w4.z, r4.z, a1); a1 = fmaf(w4.w, r4.w, a1);
                }
                {
                    float4 w4 = *(const float4*)(wd + 4 * (j4 + 2));
                    float4 r4 = *(const float4*)(&s_r[cur][4 * (j4 + 2)]);
                    a2 = fmaf(w4.x, r4.x, a2); a2 = fmaf(w4.y, r4.y, a2);
                    a2 = fmaf(w4.z, r4.z, a2); a2 = fmaf(w4.w, r4.w, a2);
                }
                {
                    float4 w4 = *(const float4*)(wd + 4 * (j4 + 3));
                    float4 r4 = *(const float4*)(&s_r[cur][4 * (j4 + 3)]);
                    a3 = fmaf(w4.x, r4.x, a3); a3 = fmaf(w4.y, r4.y, a3);
                    a3 = fmaf(w4.z, r4.z, a3); a3 = fmaf(w4.w, r4.w, a3);
                }
            }
            {   // j4 = 24 tail
                float4 w4 = *(const float4*)(wd + 96);
                float4 r4 = *(const float4*)(&s_r[cur][96]);
                a0 = fmaf(w4.x, r4.x, a0); a0 = fmaf(w4.y, r4.y, a0);
                a0 = fmaf(w4.z, r4.z, a0); a0 = fmaf(w4.w, r4.w, a0);
            }
            float acc = dan_bias;
            acc += (a0 + a1) + (a2 + a3);
            float drive = acc > 0.f ? acc : 0.f;
            float rdp = s_r[cur][80 + drow];
            dan_rn = rdp + dt * (drive - rdp);
            dan_rbd += (dan_rn - dan_rbd) * dtw;
        }

        // (2) A-lanes: full r update (Wr from LDS; 4-chain + tree, R9 order)
        float rnA = 0.f;
        if (tid < 100) {
            float acc = my_bias;
            if (tid < 20) {                       // MBON: + I_kc, tree-summed
                const float* pp = s_part2[cur] + tid * PSTR;
                float4 s01 = *(const float4*)(pp + 0)  + *(const float4*)(pp + 4);
                float4 s23 = *(const float4*)(pp + 8)  + *(const float4*)(pp + 12);
                float4 s45 = *(const float4*)(pp + 16) + *(const float4*)(pp + 20);
                float4 s67 = *(const float4*)(pp + 24) + *(const float4*)(pp + 28);
                float4 s89 = *(const float4*)(pp + 32) + *(const float4*)(pp + 36);
                float4 sab = *(const float4*)(pp + 40) + *(const float4*)(pp + 44);
                float4 t0 = s01 + s23;
                float4 t1 = s45 + s67;
                float4 t2 = s89 + sab;
                float4 u  = t0 + t1;
                u = u + t2;
                float tail = (pp[48] + pp[49]);
                acc += ((u.x + u.y) + (u.z + u.w)) + tail;
            } else if (tid < 80) {                // FBN
                acc = fmaf(we0, s_re[it], acc);
                acc = fmaf(we1, s_re[TSTEP + it], acc);
            }
            const float* wr = s_Wr + tid * WRSTR;
            float a0 = 0.f, a1 = 0.f, a2 = 0.f, a3 = 0.f;
            #pragma unroll
            for (int j4 = 0; j4 < 24; j4 += 4) {
                {
                    float4 w4 = *(const float4*)(wr + 4 * j4);
                    float4 r4 = *(const float4*)(&s_r[cur][4 * j4]);
                    a0 = fmaf(w4.x, r4.x, a0); a0 = fmaf(w4.y, r4.y, a0);
                    a0 = fmaf(w4.z, r4.z, a0); a0 = fmaf(w4.w, r4.w, a0);
                }
                {
                    float4 w4 = *(const float4*)(wr + 4 * (j4 + 1));
                    float4 r4 = *(const float4*)(&s_r[cur][4 * (j4 + 1)]);
                    a1 = fmaf(w4.x, r4.x, a1); a1 = fmaf(w4.y, r4.y, a1);
                    a1 = fmaf(w4.z, r4.z, a1); a1 = fmaf(w4.w, r4.w, a1);
                }
                {
                    float4 w4 = *(const float4*)(wr + 4 * (j4 + 2));
                    float4 r4 = *(const float4*)(&s_r[cur][4 * (j4 + 2)]);
                    a2 = fmaf(w4.x, r4.x, a2); a2 = fmaf(w4.y, r4.y, a2);
                    a2 = fmaf(w4.z, r4.z, a2); a2 = fmaf(w4.w, r4.w, a2);
                }
                {
                    float4 w4 = *(const float4*)(wr + 4 * (j4 + 3));
                    float4 r4 = *(const float4*)(&s_r[cur][4 * (j4 + 3)]);
                    a3 = fmaf(w4.x, r4.x, a3); a3 = fmaf(w4.y, r4.y, a3);
                    a3 = fmaf(w4.w, r4.w, a3); a3 = fmaf(w4.z, r4.z, a3);
                }
            }
            {   // j4 = 24 tail
                float4 w4 = *(const float4*)(wr + 96);
                float4 r4 = *(const float4*)(&s_r[cur][96]);
                a0 = fmaf(w4.x, r4.x, a0); a0 = fmaf(w4.y, r4.y, a0);
                a0 = fmaf(w4.z, r4.z, a0); a0 = fmaf(w4.w, r4.w, a0);
            }
            acc += (a0 + a1) + (a2 + a3);
            float drive = acc > 0.f ? acc : 0.f;
            float rn = r_mine + dt * (drive - r_mine);   // TAU_R = 1
            r_mine = rn;
            rnA = rn;
            s_r[nxt][tid] = rn;
            nt_store1(out_r + (size_t)(it + 1) * B * 100 + (size_t)b * 100 + tid, rn);
        }

        // (3) chunk updates: rdan/rbd via in-wave shuffle (no barrier needed;
        //     waves 2-7 reach here right after (1))
        float* oW  = out_W  + (size_t)(it + 1) * B * 4000 + (size_t)b * 4000;
        float* owt = out_wt + (size_t)(it + 1) * B * 4000 + (size_t)b * 4000;
        const float* rk_nx = s_rk + (it + 1) * NKC;
        #pragma unroll
        for (int i = 0; i < 2; ++i) {
            int c = tid + NTHR * i;
            if (c < 1000) {
                int k0 = (4 * c) % NKC;
                int m  = c / 50;
                float rdan = __shfl(dan_rn,  m);
                float rbdn = __shfl(dan_rbd, m);
                float4 rk4 = rkc[i];
                float4 rkn = *(const float4*)(rk_nx + k0);
                rkc[i] = rkn;
                float4 rb = rbkreg[i];
                rb.x += (rk4.x - rb.x) * dtw;  rb.y += (rk4.y - rb.y) * dtw;
                rb.z += (rk4.z - rb.z) * dtw;  rb.w += (rk4.w - rb.w) * dtw;
                rbkreg[i] = rb;
                float4 wt = wtreg[i];
                wt.x = fmaf(rbdn * rk4.x - rdan * rb.x, dt, wt.x);
                wt.y = fmaf(rbdn * rk4.y - rdan * rb.y, dt, wt.y);
                wt.z = fmaf(rbdn * rk4.z - rdan * rb.z, dt, wt.z);
                wt.w = fmaf(rbdn * rk4.w - rdan * rb.w, dt, wt.w);
                wtreg[i] = wt;
                float4 w = Wreg[i];
                w.x += (wt.x - w.x) * dtw;  w.y += (wt.y - w.y) * dtw;
                w.z += (wt.z - w.z) * dtw;  w.w += (wt.w - w.w) * dtw;
                w.x = fminf(fmaxf(w.x, 0.f), 0.05f);
                w.y = fminf(fmaxf(w.y, 0.f), 0.05f);
                w.z = fminf(fmaxf(w.z, 0.f), 0.05f);
                w.w = fminf(fmaxf(w.w, 0.f), 0.05f);
                Wreg[i] = w;
                s_part2[nxt][m * PSTR + (c % 50)] =
                    w.x * rkn.x + w.y * rkn.y + w.z * rkn.z + w.w * rkn.w;
                nt_store4(owt + 4 * c, wt);
                nt_store4(oW  + 4 * c, w);
            }
        }

        // (4) readout: wave-0 shuffle gather of in-register r_new MBONs
        if (tid < 64) {
            float q0 = 0.f, q1 = 0.f, q2 = 0.f, q3 = 0.f;
            #pragma unroll
            for (int mm = 0; mm < 20; mm += 4) {
                q0 = fmaf(s_Wro[mm],     __shfl(rnA, mm),     q0);
                q1 = fmaf(s_Wro[mm + 1], __shfl(rnA, mm + 1), q1);
                q2 = fmaf(s_Wro[mm + 2], __shfl(rnA, mm + 2), q2);
                q3 = fmaf(s_Wro[mm + 3], __shfl(rnA, mm + 3), q3);
            }
            if (tid == 0)
                nt_store1(out_ro + (size_t)(it + 1) * B + b, (q0 + q1) + (q2 + q3));
        }

        bar_lds();   // the ONLY barrier per step
    }
}

extern "C" void kernel_launch(void* const* d_in, const int* in_sizes, int n_in,
                              void* d_out, int out_size, void* d_ws, size_t ws_size,
                              hipStream_t stream) {
    const float* r_kc      = (const float*)d_in[0];
    const float* r_ext     = (const float*)d_in[1];
    const float* timev     = (const float*)d_in[2];
    // d_in[3] = n_batch (int scalar) — shape derived from in_sizes instead
    const float* W0_W      = (const float*)d_in[4];
    const float* W0_w      = (const float*)d_in[5];
    const float* W_recur   = (const float*)d_in[6];
    const float* W_ext     = (const float*)d_in[7];
    const float* bias      = (const float*)d_in[8];
    const float* W_readout = (const float*)d_in[9];

    const int B = in_sizes[0] / (NKC * TSTEP);   // 256
    cond_rnn_kernel<<<dim3(B), dim3(NTHR), 0, stream>>>(
        r_kc, r_ext, timev, W0_W, W0_w, W_recur, W_ext, bias, W_readout,
        (float*)d_out, B);
}

// Round 14
// 1075.524 us; speedup vs baseline: 1.0223x; 1.0218x over previous
//
#include <hip/hip_runtime.h>

// FirstOrderCondRNN: B=256 batches, T=61 (60 scan steps).
// One block per batch; all recurrent state on-chip.
// R14 = R12 single-barrier structure + SCHED_BARRIER FENCES between
// sections. R13 proved: (a) amdgpu_waves_per_eu is ignored under
// __launch_bounds__; (b) scratch traffic is IDENTICAL with/without
// wrreg[25] (R10 vs R12/R13: same 370MB/2.17GB) => the spill is
// SCHEDULER-INDUCED peak pressure (one giant scheduling region: DAN-dot
// + A-dot + 2 chunk bodies interleaved), not declared demand. Fix:
// sched_barrier(0) fences after DAN, after A, between chunk i=0/i=1,
// after chunks -> bounded regions like R9's natural 2-phase partition.
// Everything else identical to R12 (R13's j4+3 typo not carried).

#define NKC   200
#define NREC  100
#define TSTEP 61
#define NSTEP 60
#define WRSTR 108   // padded Wr row stride (16B-aligned rows, full bank coverage)
#define PSTR  52    // padded partial row stride
#define NTHR  512

typedef float vfloat4 __attribute__((ext_vector_type(4)));

__device__ __forceinline__ void SB() { __builtin_amdgcn_sched_barrier(0); }

__device__ __forceinline__ void bar_lds() {
    __builtin_amdgcn_sched_barrier(0);
    asm volatile("s_waitcnt lgkmcnt(0)");
    __builtin_amdgcn_s_barrier();
    __builtin_amdgcn_sched_barrier(0);
}

__device__ __forceinline__ void nt_store4(float* p, float4 v) {
    vfloat4 t;
    t.x = v.x; t.y = v.y; t.z = v.z; t.w = v.w;
    __builtin_nontemporal_store(t, (vfloat4*)p);
}
__device__ __forceinline__ void nt_store1(float* p, float v) {
    __builtin_nontemporal_store(v, p);
}

__global__ __launch_bounds__(NTHR, 1) void cond_rnn_kernel(
    const float* __restrict__ r_kc, const float* __restrict__ r_ext,
    const float* __restrict__ timev, const float* __restrict__ W0_W,
    const float* __restrict__ W0_w, const float* __restrict__ W_recur,
    const float* __restrict__ W_ext, const float* __restrict__ bias,
    const float* __restrict__ W_readout, float* __restrict__ out, int B)
{
    int b = blockIdx.x;
    if ((B & 7) == 0) {
        const int cpx = B >> 3;
        b = (blockIdx.x & 7) * cpx + (blockIdx.x >> 3);
    }
    const int tid  = threadIdx.x;
    const int lane = tid & 63;
    const float dt  = timev[1] - timev[0];   // 0.5
    const float dtw = dt / 5.0f;             // dt / TAU_W

    __shared__ __align__(16) float s_rk[TSTEP * NKC];     // [t][k], 48.8 KB
    __shared__ __align__(16) float s_re[128];             // [e][t]
    __shared__ __align__(16) float s_Wr[NREC * WRSTR];    // 43.2 KB (A-lanes)
    __shared__ __align__(16) float s_Wro[32];
    __shared__ __align__(16) float s_r[2][112];           // double-buffered rates
    __shared__ __align__(16) float s_Wrd[20 * 100];       // Wr DAN rows 80..99, 8 KB
    __shared__ __align__(16) float s_part2[2][20 * PSTR]; // double-buffered I_kc partials

    // ---------------- init ----------------
    const float* rk_b = r_kc + (size_t)b * (NKC * TSTEP);
    for (int f = tid; f < NKC * TSTEP; f += NTHR) {
        int k = f / TSTEP, t = f - k * TSTEP;
        s_rk[t * NKC + k] = rk_b[f];               // transpose to [t][k]
    }
    const float* re_b = r_ext + (size_t)b * (2 * TSTEP);
    if (tid < 2 * TSTEP) s_re[tid] = re_b[tid];
    for (int f = tid; f < NREC * NREC; f += NTHR) {
        int s = f / NREC, j = f - s * NREC;
        float v = W_recur[f];
        if (s < 20 && j >= 80) v = 0.f;            // Wr[:n_mbon, -n_dan:] = 0
        s_Wr[s * WRSTR + j] = v;
    }
    for (int f = tid; f < 20 * 100; f += NTHR)     // DAN rows of Wr (rows 80-99)
        s_Wrd[f] = W_recur[80 * NREC + f];

    if (tid < 20)  s_Wro[tid] = W_readout[tid];
    if (tid < 100) s_r[0][tid] = (tid < 20) ? 0.f : 0.1f;

    float my_bias = 0.f, we0 = 0.f, we1 = 0.f;
    if (tid < 100) my_bias = bias[tid];
    if (tid >= 20 && tid < 80) { we0 = W_ext[(tid - 20) * 2]; we1 = W_ext[(tid - 20) * 2 + 1]; }
    float r_mine = (tid < 20) ? 0.f : 0.1f;

    // redundant DAN state (per wave, lanes 0-19 meaningful)
    const int   drow     = (lane < 20) ? lane : 0;
    const float dan_bias = bias[80 + drow];
    float dan_rbd = 0.1f;

    // output sections
    float* out_r  = out;                              // [61][B][100]
    float* out_W  = out + (size_t)TSTEP * B * 100;    // [61][B][4000]
    float* out_wt = out_W + (size_t)TSTEP * B * 4000; // [61][B][4000]
    float* out_ro = out_wt + (size_t)TSTEP * B * 4000;// [61][B]

    float4 Wreg[2], wtreg[2], rbkreg[2], rkc[2];
    const float* W0Wb = W0_W + (size_t)b * 4000;
    const float* W0wb = W0_w + (size_t)b * 4000;
    #pragma unroll
    for (int i = 0; i < 2; ++i) {
        int c = tid + NTHR * i;
        if (c < 1000) {
            Wreg[i]  = *(const float4*)(W0Wb + 4 * c);
            wtreg[i] = *(const float4*)(W0wb + 4 * c);
            nt_store4(out_W  + (size_t)b * 4000 + 4 * c, Wreg[i]);   // t=0 dumps
            nt_store4(out_wt + (size_t)b * 4000 + 4 * c, wtreg[i]);
        }
    }
    if (tid < 100) nt_store1(out_r + (size_t)b * 100 + tid, r_mine);

    __syncthreads();

    // initial rbk = rk[:,0]; initial I_kc partials into s_part2[0]
    #pragma unroll
    for (int i = 0; i < 2; ++i) {
        int c = tid + NTHR * i;
        if (c < 1000) {
            int k0 = (4 * c) % NKC;
            int m  = c / 50;
            float4 rk0 = *(const float4*)(s_rk + k0);
            rbkreg[i] = rk0;
            rkc[i]    = rk0;
            float4 w = Wreg[i];
            s_part2[0][m * PSTR + (c % 50)] =
                w.x * rk0.x + w.y * rk0.y + w.z * rk0.z + w.w * rk0.w;
        }
    }
    if (tid == 255) {
        float ro = 0.f;
        #pragma unroll
        for (int mm = 0; mm < 20; ++mm) ro += s_Wro[mm] * s_r[0][mm];
        nt_store1(out_ro + b, ro);   // t=0 readout
    }
    __syncthreads();

    // ---------------- time loop: ONE phase, ONE barrier per step ----------------
    for (int it = 0; it < NSTEP; ++it) {
        const int cur = it & 1, nxt = cur ^ 1;

        // (1) redundant DAN rates: every wave, lanes 0-19 (bit-equal to A-lanes)
        float dan_rn;
        {
            float a0 = 0.f, a1 = 0.f, a2 = 0.f, a3 = 0.f;
            const float* wd = s_Wrd + drow * 100;
            #pragma unroll
            for (int j4 = 0; j4 < 24; j4 += 4) {
                {
                    float4 w4 = *(const float4*)(wd + 4 * j4);
                    float4 r4 = *(const float4*)(&s_r[cur][4 * j4]);
                    a0 = fmaf(w4.x, r4.x, a0); a0 = fmaf(w4.y, r4.y, a0);
                    a0 = fmaf(w4.z, r4.z, a0); a0 = fmaf(w4.w, r4.w, a0);
                }
                {
                    float4 w4 = *(const float4*)(wd + 4 * (j4 + 1));
                    float4 r4 = *(const float4*)(&s_r[cur][4 * (j4 + 1)]);
                    a1 = fmaf(w4.x, r4.x, a1); a1 = fmaf(w4.y, r4.y, a1);
                    a1 = fmaf(w4.z, r4.z, a1); a1 = fmaf(w4.w, r4.w, a1);
                }
                {
                    float4 w4 = *(const float4*)(wd + 4 * (j4 + 2));
                    float4 r4 = *(const float4*)(&s_r[cur][4 * (j4 + 2)]);
                    a2 = fmaf(w4.x, r4.x, a2); a2 = fmaf(w4.y, r4.y, a2);
                    a2 = fmaf(w4.z, r4.z, a2); a2 = fmaf(w4.w, r4.w, a2);
                }
                {
                    float4 w4 = *(const float4*)(wd + 4 * (j4 + 3));
                    float4 r4 = *(const float4*)(&s_r[cur][4 * (j4 + 3)]);
                    a3 = fmaf(w4.x, r4.x, a3); a3 = fmaf(w4.y, r4.y, a3);
                    a3 = fmaf(w4.z, r4.z, a3); a3 = fmaf(w4.w, r4.w, a3);
                }
            }
            {   // j4 = 24 tail
                float4 w4 = *(const float4*)(wd + 96);
                float4 r4 = *(const float4*)(&s_r[cur][96]);
                a0 = fmaf(w4.x, r4.x, a0); a0 = fmaf(w4.y, r4.y, a0);
                a0 = fmaf(w4.z, r4.z, a0); a0 = fmaf(w4.w, r4.w, a0);
            }
            float acc = dan_bias;
            acc += (a0 + a1) + (a2 + a3);
            float drive = acc > 0.f ? acc : 0.f;
            float rdp = s_r[cur][80 + drow];
            dan_rn = rdp + dt * (drive - rdp);
            dan_rbd += (dan_rn - dan_rbd) * dtw;
        }
        SB();   // fence: keep DAN region's pressure out of section (2)

        // (2) A-lanes: full r update (Wr from LDS; 4-chain + tree, R9 order)
        float rnA = 0.f;
        if (tid < 100) {
            float acc = my_bias;
            if (tid < 20) {                       // MBON: + I_kc, tree-summed
                const float* pp = s_part2[cur] + tid * PSTR;
                float4 s01 = *(const float4*)(pp + 0)  + *(const float4*)(pp + 4);
                float4 s23 = *(const float4*)(pp + 8)  + *(const float4*)(pp + 12);
                float4 s45 = *(const float4*)(pp + 16) + *(const float4*)(pp + 20);
                float4 s67 = *(const float4*)(pp + 24) + *(const float4*)(pp + 28);
                float4 s89 = *(const float4*)(pp + 32) + *(const float4*)(pp + 36);
                float4 sab = *(const float4*)(pp + 40) + *(const float4*)(pp + 44);
                float4 t0 = s01 + s23;
                float4 t1 = s45 + s67;
                float4 t2 = s89 + sab;
                float4 u  = t0 + t1;
                u = u + t2;
                float tail = (pp[48] + pp[49]);
                acc += ((u.x + u.y) + (u.z + u.w)) + tail;
            } else if (tid < 80) {                // FBN
                acc = fmaf(we0, s_re[it], acc);
                acc = fmaf(we1, s_re[TSTEP + it], acc);
            }
            const float* wr = s_Wr + tid * WRSTR;
            float a0 = 0.f, a1 = 0.f, a2 = 0.f, a3 = 0.f;
            #pragma unroll
            for (int j4 = 0; j4 < 24; j4 += 4) {
                {
                    float4 w4 = *(const float4*)(wr + 4 * j4);
                    float4 r4 = *(const float4*)(&s_r[cur][4 * j4]);
                    a0 = fmaf(w4.x, r4.x, a0); a0 = fmaf(w4.y, r4.y, a0);
                    a0 = fmaf(w4.z, r4.z, a0); a0 = fmaf(w4.w, r4.w, a0);
                }
                {
                    float4 w4 = *(const float4*)(wr + 4 * (j4 + 1));
                    float4 r4 = *(const float4*)(&s_r[cur][4 * (j4 + 1)]);
                    a1 = fmaf(w4.x, r4.x, a1); a1 = fmaf(w4.y, r4.y, a1);
                    a1 = fmaf(w4.z, r4.z, a1); a1 = fmaf(w4.w, r4.w, a1);
                }
                {
                    float4 w4 = *(const float4*)(wr + 4 * (j4 + 2));
                    float4 r4 = *(const float4*)(&s_r[cur][4 * (j4 + 2)]);
                    a2 = fmaf(w4.x, r4.x, a2); a2 = fmaf(w4.y, r4.y, a2);
                    a2 = fmaf(w4.z, r4.z, a2); a2 = fmaf(w4.w, r4.w, a2);
                }
                {
                    float4 w4 = *(const float4*)(wr + 4 * (j4 + 3));
                    float4 r4 = *(const float4*)(&s_r[cur][4 * (j4 + 3)]);
                    a3 = fmaf(w4.x, r4.x, a3); a3 = fmaf(w4.y, r4.y, a3);
                    a3 = fmaf(w4.z, r4.z, a3); a3 = fmaf(w4.w, r4.w, a3);
                }
            }
            {   // j4 = 24 tail
                float4 w4 = *(const float4*)(wr + 96);
                float4 r4 = *(const float4*)(&s_r[cur][96]);
                a0 = fmaf(w4.x, r4.x, a0); a0 = fmaf(w4.y, r4.y, a0);
                a0 = fmaf(w4.z, r4.z, a0); a0 = fmaf(w4.w, r4.w, a0);
            }
            acc += (a0 + a1) + (a2 + a3);
            float drive = acc > 0.f ? acc : 0.f;
            float rn = r_mine + dt * (drive - r_mine);   // TAU_R = 1
            r_mine = rn;
            rnA = rn;
            s_r[nxt][tid] = rn;
            nt_store1(out_r + (size_t)(it + 1) * B * 100 + (size_t)b * 100 + tid, rn);
        }
        SB();   // fence: keep A region's pressure out of section (3)

        // (3) chunk updates: rdan/rbd via in-wave shuffle (no barrier needed;
        //     waves 2-7 reach here right after (1)). Fence between i-bodies
        //     so their live ranges don't overlap.
        float* oW  = out_W  + (size_t)(it + 1) * B * 4000 + (size_t)b * 4000;
        float* owt = out_wt + (size_t)(it + 1) * B * 4000 + (size_t)b * 4000;
        const float* rk_nx = s_rk + (it + 1) * NKC;
        #pragma unroll
        for (int i = 0; i < 2; ++i) {
            int c = tid + NTHR * i;
            if (c < 1000) {
                int k0 = (4 * c) % NKC;
                int m  = c / 50;
                float rdan = __shfl(dan_rn,  m);
                float rbdn = __shfl(dan_rbd, m);
                float4 rk4 = rkc[i];
                float4 rkn = *(const float4*)(rk_nx + k0);
                rkc[i] = rkn;
                float4 rb = rbkreg[i];
                rb.x += (rk4.x - rb.x) * dtw;  rb.y += (rk4.y - rb.y) * dtw;
                rb.z += (rk4.z - rb.z) * dtw;  rb.w += (rk4.w - rb.w) * dtw;
                rbkreg[i] = rb;
                float4 wt = wtreg[i];
                wt.x = fmaf(rbdn * rk4.x - rdan * rb.x, dt, wt.x);
                wt.y = fmaf(rbdn * rk4.y - rdan * rb.y, dt, wt.y);
                wt.z = fmaf(rbdn * rk4.z - rdan * rb.z, dt, wt.z);
                wt.w = fmaf(rbdn * rk4.w - rdan * rb.w, dt, wt.w);
                wtreg[i] = wt;
                float4 w = Wreg[i];
                w.x += (wt.x - w.x) * dtw;  w.y += (wt.y - w.y) * dtw;
                w.z += (wt.z - w.z) * dtw;  w.w += (wt.w - w.w) * dtw;
                w.x = fminf(fmaxf(w.x, 0.f), 0.05f);
                w.y = fminf(fmaxf(w.y, 0.f), 0.05f);
                w.z = fminf(fmaxf(w.z, 0.f), 0.05f);
                w.w = fminf(fmaxf(w.w, 0.f), 0.05f);
                Wreg[i] = w;
                s_part2[nxt][m * PSTR + (c % 50)] =
                    w.x * rkn.x + w.y * rkn.y + w.z * rkn.z + w.w * rkn.w;
                nt_store4(owt + 4 * c, wt);
                nt_store4(oW  + 4 * c, w);
            }
            SB();   // fence between chunk bodies (and after the last)
        }

        // (4) readout: wave-0 shuffle gather of in-register r_new MBONs
        if (tid < 64) {
            float q0 = 0.f, q1 = 0.f, q2 = 0.f, q3 = 0.f;
            #pragma unroll
            for (int mm = 0; mm < 20; mm += 4) {
                q0 = fmaf(s_Wro[mm],     __shfl(rnA, mm),     q0);
                q1 = fmaf(s_Wro[mm + 1], __shfl(rnA, mm + 1), q1);
                q2 = fmaf(s_Wro[mm + 2], __shfl(rnA, mm + 2), q2);
                q3 = fmaf(s_Wro[mm + 3], __shfl(rnA, mm + 3), q3);
            }
            if (tid == 0)
                nt_store1(out_ro + (size_t)(it + 1) * B + b, (q0 + q1) + (q2 + q3));
        }

        bar_lds();   // the ONLY barrier per step
    }
}

extern "C" void kernel_launch(void* const* d_in, const int* in_sizes, int n_in,
                              void* d_out, int out_size, void* d_ws, size_t ws_size,
                              hipStream_t stream) {
    const float* r_kc      = (const float*)d_in[0];
    const float* r_ext     = (const float*)d_in[1];
    const float* timev     = (const float*)d_in[2];
    // d_in[3] = n_batch (int scalar) — shape derived from in_sizes instead
    const float* W0_W      = (const float*)d_in[4];
    const float* W0_w      = (const float*)d_in[5];
    const float* W_recur   = (const float*)d_in[6];
    const float* W_ext     = (const float*)d_in[7];
    const float* bias      = (const float*)d_in[8];
    const float* W_readout = (const float*)d_in[9];

    const int B = in_sizes[0] / (NKC * TSTEP);   // 256
    cond_rnn_kernel<<<dim3(B), dim3(NTHR), 0, stream>>>(
        r_kc, r_ext, timev, W0_W, W0_w, W_recur, W_ext, bias, W_readout,
        (float*)d_out, B);
}

// Round 15
// 509.884 us; speedup vs baseline: 2.1565x; 2.1094x over previous
//
#include <hip/hip_runtime.h>

// FirstOrderCondRNN: B=256 batches, T=61 (60 scan steps).
// One block per batch; all recurrent state on-chip.
// R15 = R9 champion revert (510.55us best) + one bit-safe layout tweak:
// (rdan, rbd) packed as one LDS float2 per DAN (b64 write/read instead of
// 2x b32 each side) -> ~2 LDS instrs/thread/step off Phase E's path.
// NO FP changes anywhere (absmax must stay exactly 0.25).
//
// Session ledger: single-barrier merge abandoned (4/4 scheduler-induced
// spill: R10/R12/R13/R14, VGPR=128 + GB-scale scratch regardless of fix).
// Calibrated accounting (spill rounds): non-kernel harness ~400us
// (fill 320 + misc 80); R9 kernel ~110us = max(serial recurrence ~105us
// [R8-K1, storeless], HBM write pacing ~85us). Floor ~485-505 total.

#define NKC   200
#define NREC  100
#define TSTEP 61
#define NSTEP 60
#define PSTR  52    // padded partial row stride
#define NTHR  512

typedef float vfloat4 __attribute__((ext_vector_type(4)));

// Workgroup barrier that waits only on LDS ops (lgkmcnt), leaving global
// stores in flight (no vmcnt drain). sched_barrier(0) pins program order.
__device__ __forceinline__ void bar_lds() {
    __builtin_amdgcn_sched_barrier(0);
    asm volatile("s_waitcnt lgkmcnt(0)");
    __builtin_amdgcn_s_barrier();
    __builtin_amdgcn_sched_barrier(0);
}

__device__ __forceinline__ void nt_store4(float* p, float4 v) {
    vfloat4 t;
    t.x = v.x; t.y = v.y; t.z = v.z; t.w = v.w;
    __builtin_nontemporal_store(t, (vfloat4*)p);
}
__device__ __forceinline__ void nt_store1(float* p, float v) {
    __builtin_nontemporal_store(v, p);
}

__global__ __launch_bounds__(NTHR, 1) void cond_rnn_kernel(
    const float* __restrict__ r_kc, const float* __restrict__ r_ext,
    const float* __restrict__ timev, const float* __restrict__ W0_W,
    const float* __restrict__ W0_w, const float* __restrict__ W_recur,
    const float* __restrict__ W_ext, const float* __restrict__ bias,
    const float* __restrict__ W_readout, float* __restrict__ out, int B)
{
    // XCD-aware bijective swizzle (B=256, 8 XCDs).
    int b = blockIdx.x;
    if ((B & 7) == 0) {
        const int cpx = B >> 3;                  // blocks per XCD
        b = (blockIdx.x & 7) * cpx + (blockIdx.x >> 3);
    }
    const int tid = threadIdx.x;
    const float dt  = timev[1] - timev[0];   // 0.5
    const float dtw = dt / 5.0f;             // dt / TAU_W

    __shared__ __align__(16) float s_rk[TSTEP * NKC];   // [t][k], 48.8 KB
    __shared__ __align__(16) float s_re[128];           // [e][t] (2*61)
    __shared__ __align__(16) float s_Wro[32];
    __shared__ __align__(16) float s_r[2][112];         // double-buffered rates
    __shared__ __align__(16) float s_dd[48];            // packed (rdan, rbd) per DAN
    __shared__ __align__(16) float s_part[20 * PSTR];   // I_kc partials

    // ---------------- init: stage batch inputs into LDS ----------------
    const float* rk_b = r_kc + (size_t)b * (NKC * TSTEP);
    for (int f = tid; f < NKC * TSTEP; f += NTHR) {
        int k = f / TSTEP, t = f - k * TSTEP;
        s_rk[t * NKC + k] = rk_b[f];               // transpose to [t][k]
    }
    const float* re_b = r_ext + (size_t)b * (2 * TSTEP);
    if (tid < 2 * TSTEP) s_re[tid] = re_b[tid];

    // Wr row in registers (tid<100), Wr[:20, 80:] = 0
    float4 wrreg[25];
    if (tid < 100) {
        const float* wrow = W_recur + tid * NREC;
        #pragma unroll
        for (int j4 = 0; j4 < 25; ++j4)
            wrreg[j4] = *(const float4*)(wrow + 4 * j4);
        if (tid < 20) {
            #pragma unroll
            for (int j4 = 20; j4 < 25; ++j4) {
                wrreg[j4].x = 0.f; wrreg[j4].y = 0.f;
                wrreg[j4].z = 0.f; wrreg[j4].w = 0.f;
            }
        }
    }

    if (tid < 20)  s_Wro[tid] = W_readout[tid];
    if (tid < 100) s_r[0][tid] = (tid < 20) ? 0.f : 0.1f;

    float my_bias = 0.f, we0 = 0.f, we1 = 0.f;
    if (tid < 100) my_bias = bias[tid];
    if (tid >= 20 && tid < 80) { we0 = W_ext[(tid - 20) * 2]; we1 = W_ext[(tid - 20) * 2 + 1]; }
    float rbd_mine = 0.1f;
    float r_mine   = (tid < 20) ? 0.f : 0.1f;

    // output sections
    float* out_r  = out;                              // [61][B][100]
    float* out_W  = out + (size_t)TSTEP * B * 100;    // [61][B][4000]
    float* out_wt = out_W + (size_t)TSTEP * B * 4000; // [61][B][4000]
    float* out_ro = out_wt + (size_t)TSTEP * B * 4000;// [61][B]

    // W / wt / rbk in registers: 2 float4 chunks per thread (chunk c = tid+512*i)
    float4 Wreg[2], wtreg[2], rbkreg[2], rkc[2];
    const float* W0Wb = W0_W + (size_t)b * 4000;
    const float* W0wb = W0_w + (size_t)b * 4000;
    #pragma unroll
    for (int i = 0; i < 2; ++i) {
        int c = tid + NTHR * i;
        if (c < 1000) {
            Wreg[i]  = *(const float4*)(W0Wb + 4 * c);
            wtreg[i] = *(const float4*)(W0wb + 4 * c);
            nt_store4(out_W  + (size_t)b * 4000 + 4 * c, Wreg[i]);   // t=0 dumps
            nt_store4(out_wt + (size_t)b * 4000 + 4 * c, wtreg[i]);
        }
    }
    if (tid < 100) nt_store1(out_r + (size_t)b * 100 + tid, r_mine);

    __syncthreads();

    // initial rbk = rk[:,0]; initial I_kc partials = dot(W0, rk_0);
    // rkc carries rk row `it` for this thread's chunks.
    #pragma unroll
    for (int i = 0; i < 2; ++i) {
        int c = tid + NTHR * i;
        if (c < 1000) {
            int k0 = (4 * c) % NKC;
            int m  = c / 50;
            float4 rk0 = *(const float4*)(s_rk + k0);   // t = 0 row
            rbkreg[i] = rk0;
            rkc[i]    = rk0;
            float4 w = Wreg[i];
            s_part[m * PSTR + (c % 50)] =
                w.x * rk0.x + w.y * rk0.y + w.z * rk0.z + w.w * rk0.w;
        }
    }
    if (tid == 255) {
        float ro = 0.f;
        #pragma unroll
        for (int mm = 0; mm < 20; ++mm) ro += s_Wro[mm] * s_r[0][mm];
        nt_store1(out_ro + b, ro);   // t=0 readout
    }
    __syncthreads();

    // ---------------- time loop ----------------
    for (int it = 0; it < NSTEP; ++it) {
        const int cur = it & 1, nxt = cur ^ 1;

        // Phase A: drive = bias + Wr·r + I_tot ; r_new ; rbd_new
        if (tid < 100) {
            float acc = my_bias;
            if (tid < 20) {                       // MBON: + I_kc, tree-summed
                const float* pp = s_part + tid * PSTR;
                float4 s01 = *(const float4*)(pp + 0)  + *(const float4*)(pp + 4);
                float4 s23 = *(const float4*)(pp + 8)  + *(const float4*)(pp + 12);
                float4 s45 = *(const float4*)(pp + 16) + *(const float4*)(pp + 20);
                float4 s67 = *(const float4*)(pp + 24) + *(const float4*)(pp + 28);
                float4 s89 = *(const float4*)(pp + 32) + *(const float4*)(pp + 36);
                float4 sab = *(const float4*)(pp + 40) + *(const float4*)(pp + 44);
                float4 t0 = s01 + s23;
                float4 t1 = s45 + s67;
                float4 t2 = s89 + sab;
                float4 u  = t0 + t1;
                u = u + t2;
                float tail = (pp[48] + pp[49]);
                acc += ((u.x + u.y) + (u.z + u.w)) + tail;
            } else if (tid < 80) {                // FBN: + W_ext · re_t
                acc = fmaf(we0, s_re[it], acc);
                acc = fmaf(we1, s_re[TSTEP + it], acc);
            }
            // Wr·r with 4 independent accumulator chains (25 j4 -> 4 strided)
            float a0 = 0.f, a1 = 0.f, a2 = 0.f, a3 = 0.f;
            #pragma unroll
            for (int j4 = 0; j4 < 24; j4 += 4) {
                {
                    float4 w4 = wrreg[j4];
                    float4 r4 = *(const float4*)(&s_r[cur][4 * j4]);
                    a0 = fmaf(w4.x, r4.x, a0); a0 = fmaf(w4.y, r4.y, a0);
                    a0 = fmaf(w4.z, r4.z, a0); a0 = fmaf(w4.w, r4.w, a0);
                }
                {
                    float4 w4 = wrreg[j4 + 1];
                    float4 r4 = *(const float4*)(&s_r[cur][4 * (j4 + 1)]);
                    a1 = fmaf(w4.x, r4.x, a1); a1 = fmaf(w4.y, r4.y, a1);
                    a1 = fmaf(w4.z, r4.z, a1); a1 = fmaf(w4.w, r4.w, a1);
                }
                {
                    float4 w4 = wrreg[j4 + 2];
                    float4 r4 = *(const float4*)(&s_r[cur][4 * (j4 + 2)]);
                    a2 = fmaf(w4.x, r4.x, a2); a2 = fmaf(w4.y, r4.y, a2);
                    a2 = fmaf(w4.z, r4.z, a2); a2 = fmaf(w4.w, r4.w, a2);
                }
                {
                    float4 w4 = wrreg[j4 + 3];
                    float4 r4 = *(const float4*)(&s_r[cur][4 * (j4 + 3)]);
                    a3 = fmaf(w4.x, r4.x, a3); a3 = fmaf(w4.y, r4.y, a3);
                    a3 = fmaf(w4.z, r4.z, a3); a3 = fmaf(w4.w, r4.w, a3);
                }
            }
            {   // j4 = 24 tail
                float4 w4 = wrreg[24];
                float4 r4 = *(const float4*)(&s_r[cur][96]);
                a0 = fmaf(w4.x, r4.x, a0); a0 = fmaf(w4.y, r4.y, a0);
                a0 = fmaf(w4.z, r4.z, a0); a0 = fmaf(w4.w, r4.w, a0);
            }
            acc += (a0 + a1) + (a2 + a3);
            float drive = acc > 0.f ? acc : 0.f;  // relu
            float rn = r_mine + dt * (drive - r_mine);   // TAU_R = 1
            r_mine = rn;
            s_r[nxt][tid] = rn;
            nt_store1(out_r + (size_t)(it + 1) * B * 100 + (size_t)b * 100 + tid, rn);
            if (tid >= 80) {                      // DAN: rbd update, packed store
                rbd_mine += (rn - rbd_mine) * dtw;
                *(float2*)(s_dd + 2 * (tid - 80)) = make_float2(rn, rbd_mine);
            }
        }
        bar_lds();

        // Phase E: rbk / wt / W updates, next-step partials, global stores
        float* oW  = out_W  + (size_t)(it + 1) * B * 4000 + (size_t)b * 4000;
        float* owt = out_wt + (size_t)(it + 1) * B * 4000 + (size_t)b * 4000;
        const float* rk_nx  = s_rk + (it + 1) * NKC;
        #pragma unroll
        for (int i = 0; i < 2; ++i) {
            int c = tid + NTHR * i;
            if (c < 1000) {
                int k0 = (4 * c) % NKC;
                int m  = c / 50;
                float4 rk4 = rkc[i];                        // carried row `it`
                float4 rkn = *(const float4*)(rk_nx + k0);  // row `it+1`
                rkc[i] = rkn;
                float2 dd  = *(const float2*)(s_dd + 2 * m); // (rdan, rbd) one b64
                float rdan = dd.x;
                float rbdn = dd.y;
                float4 rb = rbkreg[i];
                rb.x += (rk4.x - rb.x) * dtw;  rb.y += (rk4.y - rb.y) * dtw;
                rb.z += (rk4.z - rb.z) * dtw;  rb.w += (rk4.w - rb.w) * dtw;
                rbkreg[i] = rb;
                float4 wt = wtreg[i];
                wt.x = fmaf(rbdn * rk4.x - rdan * rb.x, dt, wt.x);
                wt.y = fmaf(rbdn * rk4.y - rdan * rb.y, dt, wt.y);
                wt.z = fmaf(rbdn * rk4.z - rdan * rb.z, dt, wt.z);
                wt.w = fmaf(rbdn * rk4.w - rdan * rb.w, dt, wt.w);
                wtreg[i] = wt;
                float4 w = Wreg[i];
                w.x += (wt.x - w.x) * dtw;  w.y += (wt.y - w.y) * dtw;
                w.z += (wt.z - w.z) * dtw;  w.w += (wt.w - w.w) * dtw;
                w.x = fminf(fmaxf(w.x, 0.f), 0.05f);
                w.y = fminf(fmaxf(w.y, 0.f), 0.05f);
                w.z = fminf(fmaxf(w.z, 0.f), 0.05f);
                w.w = fminf(fmaxf(w.w, 0.f), 0.05f);
                Wreg[i] = w;
                // partial dot for NEXT step's I_kc (uses rk at it+1)
                s_part[m * PSTR + (c % 50)] =
                    w.x * rkn.x + w.y * rkn.y + w.z * rkn.z + w.w * rkn.w;
                nt_store4(owt + 4 * c, wt);
                nt_store4(oW  + 4 * c, w);
            }
        }
        if (tid == 255) {   // readout from r_new MBONs (tree)
            const float* rr = &s_r[nxt][0];
            float q0 = 0.f, q1 = 0.f, q2 = 0.f, q3 = 0.f;
            #pragma unroll
            for (int mm = 0; mm < 20; mm += 4) {
                q0 = fmaf(s_Wro[mm],     rr[mm],     q0);
                q1 = fmaf(s_Wro[mm + 1], rr[mm + 1], q1);
                q2 = fmaf(s_Wro[mm + 2], rr[mm + 2], q2);
                q3 = fmaf(s_Wro[mm + 3], rr[mm + 3], q3);
            }
            nt_store1(out_ro + (size_t)(it + 1) * B + b, (q0 + q1) + (q2 + q3));
        }
        bar_lds();
    }
}

extern "C" void kernel_launch(void* const* d_in, const int* in_sizes, int n_in,
                              void* d_out, int out_size, void* d_ws, size_t ws_size,
                              hipStream_t stream) {
    const float* r_kc      = (const float*)d_in[0];
    const float* r_ext     = (const float*)d_in[1];
    const float* timev     = (const float*)d_in[2];
    // d_in[3] = n_batch (int scalar) — shape derived from in_sizes instead
    const float* W0_W      = (const float*)d_in[4];
    const float* W0_w      = (const float*)d_in[5];
    const float* W_recur   = (const float*)d_in[6];
    const float* W_ext     = (const float*)d_in[7];
    const float* bias      = (const float*)d_in[8];
    const float* W_readout = (const float*)d_in[9];

    const int B = in_sizes[0] / (NKC * TSTEP);   // 256
    cond_rnn_kernel<<<dim3(B), dim3(NTHR), 0, stream>>>(
        r_kc, r_ext, timev, W0_W, W0_w, W_recur, W_ext, bias, W_readout,
        (float*)d_out, B);
}